// Round 12
// baseline (462.258 us; speedup 1.0000x reference)
//
#include <hip/hip_runtime.h>

typedef unsigned short ushort_t;
typedef __attribute__((ext_vector_type(8))) short bf16x8;
typedef __attribute__((ext_vector_type(4))) float f32x4;
typedef __attribute__((ext_vector_type(8))) unsigned short ushort8;

// Problem geometry (compile-time)
constexpr int BB   = 8;
constexpr int CC   = 256;
constexpr int OUTC = 256;
constexpr int KK   = 7;
constexpr int LL   = 2048;
constexpr int PADc = 3;
constexpr int KD   = CC * KK;        // 1792 reduction dim
constexpr int MOFF = CC * KK * 2;    // 3584 offset-conv out channels
constexpr int NTOT = BB * LL;        // 16384
constexpr int NKSTEPS = KD / 32;     // 56
constexpr int LP   = LL + 6;         // 2054 padded length
constexpr int ABUF = 4096;           // A ring buffer (8 KB) in ushorts

__device__ __forceinline__ ushort_t f2bf(float f) {
    unsigned u = __float_as_uint(f);
    unsigned r = (u + 0x7fffu + ((u >> 16) & 1u)) >> 16;  // RNE
    return (ushort_t)r;
}

// -------------------- cast f32 -> bf16 (vectorized, main-conv weight) --------------------
__global__ __launch_bounds__(256) void cast_k(const float4* __restrict__ src,
                                              ushort_t* __restrict__ dst, int n4) {
    int i = blockIdx.x * 256 + threadIdx.x;
    if (i >= n4) return;
    float4 v = src[i];
    ushort4 o;
    o.x = f2bf(v.x); o.y = f2bf(v.y); o.z = f2bf(v.z); o.w = f2bf(v.w);
    *(ushort4*)(dst + (size_t)i * 4) = o;
}

// ------ cast + permute w_off into c-major/tap-inner K layout ------
// K index q: chunk ks = q>>5 (cs = ks/7, tap = ks%7), cl = q&31 -> (c = cs*32+cl, kk = tap)
__global__ __launch_bounds__(256) void castperm_woff(const float* __restrict__ src,
                                                     ushort_t* __restrict__ dst) {
    int i = blockIdx.x * 256 + threadIdx.x;
    if (i >= MOFF * KD) return;
    int dr  = i / KD;
    int q   = i - dr * KD;
    int cs   = q / 224;
    int r224 = q - cs * 224;
    int tap  = r224 >> 5;
    int cl   = r224 & 31;
    int c = cs * 32 + cl;
    int r = (dr & 1) ? (KD + (dr >> 1)) : (dr >> 1);
    dst[i] = f2bf(src[(r * 256 + c) * 7 + tap]);
}

// -------------------- padded transpose: xp[b][l+3][c] = x[b][c][l] --------------------
__global__ __launch_bounds__(256) void xpose_k(const float* __restrict__ x,
                                               ushort_t* __restrict__ xp) {
    __shared__ float tile[32][257];
    int bid = blockIdx.x;                 // 8 b x 8 ltiles x 8 cchunks = 512
    int b  = bid >> 6;
    int l0 = ((bid >> 3) & 7) * 256;
    int c0 = (bid & 7) * 32;
    int tid = threadIdx.x;
    const float* xb = x + (size_t)b * (CC * LL);
    ushort_t* xpb = xp + (size_t)b * (LP * 256);
#pragma unroll 4
    for (int k = 0; k < 32; ++k)
        tile[k][tid] = xb[(size_t)(c0 + k) * LL + l0 + tid];
    __syncthreads();
    int lp = l0 + tid + 3;
#pragma unroll
    for (int q = 0; q < 8; ++q) {
        ushort4 v;
        v.x = f2bf(tile[4 * q + 0][tid]);
        v.y = f2bf(tile[4 * q + 1][tid]);
        v.z = f2bf(tile[4 * q + 2][tid]);
        v.w = f2bf(tile[4 * q + 3][tid]);
        *(ushort4*)(xpb + (size_t)lp * 256 + c0 + 4 * q) = v;
    }
    if ((bid & 63) == 0) {
#pragma unroll
        for (int r = 0; r < 6; ++r) {
            int glp = (r < 3) ? r : (2048 + r);
            xpb[glp * 256 + tid] = 0;
        }
    }
}

// -------------------- async global->LDS 16B --------------------
__device__ __forceinline__ void load_lds16(const ushort_t* g, ushort_t* l) {
    __builtin_amdgcn_global_load_lds(
        (const __attribute__((address_space(1))) unsigned int*)g,
        (__attribute__((address_space(3))) unsigned int*)l, 16, 0, 0);
}

// ==================== 128x256 GEMM: A via LDS ring-3, B global->register ====================
// 8 waves (2M x 4N), per-wave 64x64 (acc[4][4], 16 MFMA/kstep).
// A: ring-3 x 8KB = 24KB LDS, staged distance 2, swizzle u = kh^((r15>>1)&3) (verified).
// B: per-lane 16B fragment loads straight from xp (L2-resident window), ping-pong
//    register sets; bq(kt+1) loaded during kstep kt (~1600cyc cover vs ~200-900 latency).
// Per-kstep FIFO: [4x B(kt+1)][1x A-stage(kt+2)]; end gate vmcnt(5)+sched_barrier+s_barrier
// drains A(kt+1) (6th-newest) before any wave reads its LDS; compiler's exact counted
// wait covers bqC (older than the 5 newest). Prologue gate vmcnt(1); tail vmcnt(4)/none.
__device__ __forceinline__ void stageAp(ushort_t* ldsbuf, const ushort_t* __restrict__ A,
                                        int m0, int kt, int tid) {
    int g = (tid & 3) ^ ((tid >> 3) & 3);    // pre-swizzled global 16B-slot
    int row = tid >> 2;                       // 0..127
    load_lds16(A + (size_t)(m0 + row) * KD + kt * 32 + g * 8,
               ldsbuf + (tid >> 6) * 512);
}

__device__ __forceinline__ void loadB(bf16x8 (&bq)[4], const ushort_t* __restrict__ xpb,
                                      int nrow, int kt, int kh) {
    int cs = kt / 7, tap = kt - cs * 7;       // uniform -> SALU
    const ushort_t* bb = xpb + (size_t)(nrow + tap) * 256 + cs * 32 + kh * 8;
#pragma unroll
    for (int j = 0; j < 4; ++j)
        bq[j] = *(const bf16x8*)(bb + (size_t)j * 16 * 256);
}

template <int MODE>  // 0 steady; 1 = kt==54 (B-load only, gate vmcnt(4)); 2 = kt==55 (MFMA only)
__device__ __forceinline__ void kstepR(const ushort_t* __restrict__ A,
                                       const ushort_t* __restrict__ xpb,
                                       ushort_t* lds, int m0, int nrow, int kt,
                                       int tid, int wr, int r15, int kh, int u,
                                       bf16x8 (&bqC)[4], bf16x8 (&bqN)[4],
                                       f32x4 (&acc)[4][4]) {
    // entry invariant: previous gate+barrier passed; A buf[kt%3] visible
    const ushort_t* pa = lds + (size_t)(kt % 3) * ABUF + (wr * 64 + r15) * 32 + u * 8;
    bf16x8 af[4];
#pragma unroll
    for (int i = 0; i < 4; ++i) af[i] = *(const bf16x8*)(pa + i * 512);
    if (MODE != 2) loadB(bqN, xpb, nrow, kt + 1, kh);          // 4 VM loads
    if (MODE == 0) stageAp(lds + (size_t)((kt + 2) % 3) * ABUF, A, m0, kt + 2, tid);
    __builtin_amdgcn_s_setprio(1);
#pragma unroll
    for (int i = 0; i < 4; ++i)
#pragma unroll
        for (int j = 0; j < 4; ++j)
            acc[i][j] = __builtin_amdgcn_mfma_f32_16x16x32_bf16(af[i], bqC[j], acc[i][j], 0, 0, 0);
    __builtin_amdgcn_s_setprio(0);
    if (MODE == 0)      asm volatile("s_waitcnt vmcnt(5)" ::: "memory");
    else if (MODE == 1) asm volatile("s_waitcnt vmcnt(4)" ::: "memory");
    if (MODE != 2) {
        __builtin_amdgcn_sched_barrier(0);
        __builtin_amdgcn_s_barrier();
    }
}

__global__ __launch_bounds__(512, 4) void gemm128r_off_fused(const ushort_t* __restrict__ A,
                                                             const ushort_t* __restrict__ xp,
                                                             const float* __restrict__ boff,
                                                             const float* __restrict__ x,
                                                             ushort_t* __restrict__ s) {
    __shared__ __align__(16) ushort_t lds[18432];        // max(24KB A-ring, 36KB epi tile)
    constexpr int NT = NTOT / 256;                        // 64 n-tiles
    constexpr int NWG = (MOFF / 128) * NT;                // 1792 (%8==0)
    int bid = blockIdx.x;
    int wg = (bid & 7) * (NWG / 8) + (bid >> 3);          // XCD-bijective swizzle
    int mt = wg / NT, nt = wg % NT;
    int m0 = mt * 128, n0 = nt * 256;
    int tid = threadIdx.x, wid = tid >> 6, lane = tid & 63;
    int wr = wid >> 2, wc = wid & 3;
    int r15 = lane & 15, kh = lane >> 4;
    int u = kh ^ ((r15 >> 1) & 3);                        // swizzled A read slot

    const ushort_t* xpb = xp + (size_t)(n0 >> 11) * (LP * 256);
    int nrow = (n0 & 2047) + wc * 64 + r15;               // per-lane B row base

    f32x4 acc[4][4] = {};
    bf16x8 bqA[4], bqB[4];

    // prologue: [B(0) x4][A(0) x1][A(1) x1]; vmcnt(1) drains B(0)+A(0), leaves A(1)
    loadB(bqA, xpb, nrow, 0, kh);
    stageAp(lds,        A, m0, 0, tid);
    stageAp(lds + ABUF, A, m0, 1, tid);
    asm volatile("s_waitcnt vmcnt(1)" ::: "memory");
    __builtin_amdgcn_sched_barrier(0);
    __builtin_amdgcn_s_barrier();

#pragma unroll 1
    for (int p = 0; p < 27; ++p) {
        kstepR<0>(A, xpb, lds, m0, nrow, 2 * p,     tid, wr, r15, kh, u, bqA, bqB, acc);
        kstepR<0>(A, xpb, lds, m0, nrow, 2 * p + 1, tid, wr, r15, kh, u, bqB, bqA, acc);
    }
    kstepR<1>(A, xpb, lds, m0, nrow, 54, tid, wr, r15, kh, u, bqA, bqB, acc);
    kstepR<2>(A, xpb, lds, m0, nrow, 55, tid, wr, r15, kh, u, bqB, bqA, acc);

    // ---- fused epilogue: bias + sigmoid + deformable lerp -> LDS transpose tile ----
    __syncthreads();                     // K-loop LDS dead
    ushort_t* st = lds;                  // [256 n][72 pitch] bf16 tile (36 KB)
#pragma unroll
    for (int i = 0; i < 4; ++i) {
        int mloc = wr * 64 + i * 16 + kh * 4;             // local m (even)
        int ckb  = (m0 + mloc) >> 1;                       // global ck base (2 cks)
        int ckl  = mloc >> 1;                              // local ck (even, 0..62)
        float bo0 = boff[ckb],     bm0 = boff[KD + ckb];
        float bo1 = boff[ckb + 1], bm1 = boff[KD + ckb + 1];
        int c0 = ckb / 7,       kk0 = ckb - c0 * 7;
        int c1 = (ckb + 1) / 7, kk1 = (ckb + 1) - c1 * 7;
#pragma unroll
        for (int j = 0; j < 4; ++j) {
            int nl = wc * 64 + j * 16 + r15;
            int n = n0 + nl;
            int b = n >> 11, l = n & 2047;
            const float* xb_ = x + (size_t)b * (CC * LL);
            f32x4 v = acc[i][j];
            ushort2 o2;
#pragma unroll
            for (int p = 0; p < 2; ++p) {
                float offv = v[2 * p]     + (p ? bo1 : bo0);
                float mpre = v[2 * p + 1] + (p ? bm1 : bm0);
                int c = p ? c1 : c0, kk = p ? kk1 : kk0;
                float mask = 1.0f / (1.0f + __expf(-mpre));
                float pos = offv + (float)(l - PADc + kk);
                float p0f = floorf(pos);
                float frac = pos - p0f;
                int p0 = (int)p0f;
                const float* xr = xb_ + (size_t)c * LL;
                float x0 = ((unsigned)p0 < (unsigned)LL) ? xr[p0] : 0.0f;
                float x1 = ((unsigned)(p0 + 1) < (unsigned)LL) ? xr[p0 + 1] : 0.0f;
                float sv = (x0 + (x1 - x0) * frac) * mask;
                if (p) o2.y = f2bf(sv); else o2.x = f2bf(sv);
            }
            *(ushort2*)(st + nl * 72 + ckl) = o2;
        }
    }
    __syncthreads();
    // coalesced store-back: 256 rows x 128B; 8 lanes x ushort8 per row, 4 passes
    int srow = tid >> 3;                 // 0..63
    int scol = tid & 7;                  // 0..7
    int ck0g = m0 >> 1;
#pragma unroll
    for (int pass = 0; pass < 4; ++pass) {
        int nl = pass * 64 + srow;
        ushort8 v8 = *(const ushort8*)(st + nl * 72 + scol * 8);
        *(ushort8*)(s + (size_t)(n0 + nl) * KD + ck0g + scol * 8) = v8;
    }
}

// ==================== 128x128 counted-vmcnt GEMM (main conv, unchanged) ====================
__device__ __forceinline__ void stage128(ushort_t* ldsbuf,
                                         const ushort_t* __restrict__ A,
                                         const ushort_t* __restrict__ Bt,
                                         int m0, int n0, int kt,
                                         int wid, int lane) {
    int t = wid * 64 + lane;
    int g = (t & 3) ^ ((t >> 3) & 3);
#pragma unroll
    for (int j = 0; j < 2; ++j) {
        int row = j * 64 + (t >> 2);
        load_lds16(A  + (size_t)(m0 + row) * KD + kt * 32 + g * 8,
                   ldsbuf + j * 2048 + wid * 512);
        load_lds16(Bt + (size_t)(n0 + row) * KD + kt * 32 + g * 8,
                   ldsbuf + 4096 + j * 2048 + wid * 512);
    }
}

template <int VMCN>
__device__ __forceinline__ void kstep128(const ushort_t* __restrict__ A,
                                         const ushort_t* __restrict__ Bt,
                                         ushort_t* lds, int m0, int n0, int kt,
                                         int wid, int lane, int wr, int wc,
                                         int r15, int u, f32x4 (&acc)[4][4]) {
    asm volatile("s_waitcnt vmcnt(%0)" :: "n"(VMCN) : "memory");
    __builtin_amdgcn_s_barrier();
    const ushort_t* buf = lds + (size_t)(kt & 3) * 8192;
    const ushort_t* pa = buf + (wr * 64 + r15) * 32 + u * 8;
    const ushort_t* pb = buf + 4096 + (wc * 64 + r15) * 32 + u * 8;
    bf16x8 af[4], bq[4];
#pragma unroll
    for (int i = 0; i < 4; ++i) af[i] = *(const bf16x8*)(pa + i * 512);
#pragma unroll
    for (int j = 0; j < 4; ++j) bq[j] = *(const bf16x8*)(pb + j * 512);
    if (kt + 3 < NKSTEPS)
        stage128(lds + (size_t)((kt + 3) & 3) * 8192, A, Bt, m0, n0, kt + 3, wid, lane);
    __builtin_amdgcn_s_setprio(1);
#pragma unroll
    for (int i = 0; i < 4; ++i)
#pragma unroll
        for (int j = 0; j < 4; ++j)
            acc[i][j] = __builtin_amdgcn_mfma_f32_16x16x32_bf16(af[i], bq[j], acc[i][j], 0, 0, 0);
    __builtin_amdgcn_s_setprio(0);
}

__global__ __launch_bounds__(256, 2) void gemm128_out(const ushort_t* __restrict__ A,
                                                      const ushort_t* __restrict__ Bt,
                                                      const float* __restrict__ bvec,
                                                      float* __restrict__ Dout) {
    __shared__ __align__(16) ushort_t lds[4 * 8192];     // 64 KiB ring
    constexpr int NT = NTOT / 128;
    constexpr int NWG = (OUTC / 128) * NT;                // 256 (%8==0)
    int bid = blockIdx.x;
    int wg = (bid & 7) * (NWG / 8) + (bid >> 3);
    int mt = wg / NT, nt = wg % NT;
    int m0 = mt * 128, n0 = nt * 128;
    int tid = threadIdx.x, wid = tid >> 6, lane = tid & 63;
    int wr = wid >> 1, wc = wid & 1;
    int r15 = lane & 15, kh = lane >> 4;
    int u = kh ^ ((r15 >> 1) & 3);

    f32x4 acc[4][4] = {};

    stage128(lds,            A, Bt, m0, n0, 0, wid, lane);
    stage128(lds + 8192,     A, Bt, m0, n0, 1, wid, lane);
    stage128(lds + 2 * 8192, A, Bt, m0, n0, 2, wid, lane);

    for (int kt = 0; kt < NKSTEPS - 2; ++kt)
        kstep128<8>(A, Bt, lds, m0, n0, kt, wid, lane, wr, wc, r15, u, acc);
    kstep128<4>(A, Bt, lds, m0, n0, NKSTEPS - 2, wid, lane, wr, wc, r15, u, acc);
    kstep128<0>(A, Bt, lds, m0, n0, NKSTEPS - 1, wid, lane, wr, wc, r15, u, acc);

    int rbase = kh * 4;
#pragma unroll
    for (int i = 0; i < 4; ++i)
#pragma unroll
        for (int j = 0; j < 4; ++j) {
            int m = m0 + wr * 64 + i * 16 + rbase;
            int n = n0 + wc * 64 + j * 16 + r15;
            int b = n >> 11, l = n & 2047;
#pragma unroll
            for (int r = 0; r < 4; ++r) {
                float val = acc[i][j][r] + bvec[m + r];
                Dout[((size_t)(b * OUTC + (m + r))) * LL + l] = val;
            }
        }
}

// -------------------- launch --------------------
extern "C" void kernel_launch(void* const* d_in, const int* in_sizes, int n_in,
                              void* d_out, int out_size, void* d_ws, size_t ws_size,
                              hipStream_t stream) {
    const float* x      = (const float*)d_in[0];   // (8,256,2048)
    const float* w_off  = (const float*)d_in[1];   // (3584,256,7)
    const float* b_off  = (const float*)d_in[2];   // (3584,)
    const float* weight = (const float*)d_in[3];   // (256,256,7)
    const float* bias   = (const float*)d_in[4];   // (256,)
    float* out = (float*)d_out;                    // (8,256,2048)

    ushort_t* w = (ushort_t*)d_ws;
    ushort_t* wb  = w;                       // MOFF*KD   = 6,422,528 (c-major/tap-inner, row-permuted)
    ushort_t* wtb = wb  + MOFF * KD;         // OUTC*KD   =   458,752
    ushort_t* xp  = wtb + OUTC * KD;         // BB*LP*256 = 4,206,592 (padded transpose)
    ushort_t* s   = xp  + BB * LP * 256;     // NTOT*KD   = 29,360,128

    castperm_woff<<<(MOFF * KD + 255) / 256, 256, 0, stream>>>(w_off, wb);
    cast_k<<<(114688 + 255) / 256, 256, 0, stream>>>((const float4*)weight, wtb, 114688);
    xpose_k<<<512, 256, 0, stream>>>(x, xp);

    // offset conv (A via LDS ring-3, B global->reg ping-pong) + fused sampling
    gemm128r_off_fused<<<(MOFF / 128) * (NTOT / 256), 512, 0, stream>>>(wb, xp, b_off, x, s);

    // main conv: [256 x 1792] * [1792 x 16384]
    gemm128_out<<<(OUTC / 128) * (NTOT / 128), 256, 0, stream>>>(wtb, s, bias, out);
}

// Round 13
// 266.628 us; speedup vs baseline: 1.7337x; 1.7337x over previous
//
#include <hip/hip_runtime.h>

typedef unsigned short ushort_t;
typedef __attribute__((ext_vector_type(8))) short bf16x8;
typedef __attribute__((ext_vector_type(4))) float f32x4;
typedef __attribute__((ext_vector_type(8))) unsigned short ushort8;

// Problem geometry (compile-time)
constexpr int BB   = 8;
constexpr int CC   = 256;
constexpr int OUTC = 256;
constexpr int KK   = 7;
constexpr int LL   = 2048;
constexpr int PADc = 3;
constexpr int KD   = CC * KK;        // 1792 reduction dim
constexpr int MOFF = CC * KK * 2;    // 3584 offset-conv out channels
constexpr int NTOT = BB * LL;        // 16384
constexpr int NKSTEPS = KD / 32;     // 56
constexpr int LP   = LL + 6;         // 2054 padded length
constexpr int BUFU = 12288;          // ring buffer (24 KB: A 8K + B 16K) in ushorts

__device__ __forceinline__ ushort_t f2bf(float f) {
    unsigned u = __float_as_uint(f);
    unsigned r = (u + 0x7fffu + ((u >> 16) & 1u)) >> 16;  // RNE
    return (ushort_t)r;
}

// -------------------- cast f32 -> bf16 (vectorized, main-conv weight) --------------------
__global__ __launch_bounds__(256) void cast_k(const float4* __restrict__ src,
                                              ushort_t* __restrict__ dst, int n4) {
    int i = blockIdx.x * 256 + threadIdx.x;
    if (i >= n4) return;
    float4 v = src[i];
    ushort4 o;
    o.x = f2bf(v.x); o.y = f2bf(v.y); o.z = f2bf(v.z); o.w = f2bf(v.w);
    *(ushort4*)(dst + (size_t)i * 4) = o;
}

// ------ cast + permute w_off into c-major/tap-inner K layout ------
// K index q: chunk ks = q>>5 (cs = ks/7, tap = ks%7), cl = q&31 -> (c = cs*32+cl, kk = tap)
__global__ __launch_bounds__(256) void castperm_woff(const float* __restrict__ src,
                                                     ushort_t* __restrict__ dst) {
    int i = blockIdx.x * 256 + threadIdx.x;
    if (i >= MOFF * KD) return;
    int dr  = i / KD;
    int q   = i - dr * KD;
    int cs   = q / 224;
    int r224 = q - cs * 224;
    int tap  = r224 >> 5;
    int cl   = r224 & 31;
    int c = cs * 32 + cl;
    int r = (dr & 1) ? (KD + (dr >> 1)) : (dr >> 1);
    dst[i] = f2bf(src[(r * 256 + c) * 7 + tap]);
}

// -------------------- padded transpose: xp[b][l+3][c] = x[b][c][l] --------------------
__global__ __launch_bounds__(256) void xpose_k(const float* __restrict__ x,
                                               ushort_t* __restrict__ xp) {
    __shared__ float tile[32][257];
    int bid = blockIdx.x;                 // 8 b x 8 ltiles x 8 cchunks = 512
    int b  = bid >> 6;
    int l0 = ((bid >> 3) & 7) * 256;
    int c0 = (bid & 7) * 32;
    int tid = threadIdx.x;
    const float* xb = x + (size_t)b * (CC * LL);
    ushort_t* xpb = xp + (size_t)b * (LP * 256);
#pragma unroll 4
    for (int k = 0; k < 32; ++k)
        tile[k][tid] = xb[(size_t)(c0 + k) * LL + l0 + tid];
    __syncthreads();
    int lp = l0 + tid + 3;
#pragma unroll
    for (int q = 0; q < 8; ++q) {
        ushort4 v;
        v.x = f2bf(tile[4 * q + 0][tid]);
        v.y = f2bf(tile[4 * q + 1][tid]);
        v.z = f2bf(tile[4 * q + 2][tid]);
        v.w = f2bf(tile[4 * q + 3][tid]);
        *(ushort4*)(xpb + (size_t)lp * 256 + c0 + 4 * q) = v;
    }
    if ((bid & 63) == 0) {
#pragma unroll
        for (int r = 0; r < 6; ++r) {
            int glp = (r < 3) ? r : (2048 + r);
            xpb[glp * 256 + tid] = 0;
        }
    }
}

// -------------------- async global->LDS 16B --------------------
__device__ __forceinline__ void load_lds16(const ushort_t* g, ushort_t* l) {
    __builtin_amdgcn_global_load_lds(
        (const __attribute__((address_space(1))) unsigned int*)g,
        (__attribute__((address_space(3))) unsigned int*)l, 16, 0, 0);
}

// ==================== 128x256 counted-vmcnt GEMM + tap-B (c-major) + fused sampling ====================
// ROUND-9 VERIFIED OPTIMUM (237 us, MfmaUtil 41.5%, FETCH 136MB) — restored verbatim.
// Tile M=128 x N=256, 8 waves (2M x 4N), per-wave 64x64 (acc[4][4]).
// Ring-3 LDS (3 x 24 KB = 72 KB -> 2 blocks/CU), ONE vmcnt gate + ONE barrier per
// BK=32 step, stage distance 2, per-lane 3 loads/kstep -> gates vmcnt(3)/(3)/(0).
// K order is c-major/tap-inner: kt -> cs = kt/7, tap = kt%7, so consecutive ksteps
// re-read a 1-row-shifted xp window (L2-hot) instead of 7 separated tap passes.
__device__ __forceinline__ void stageA128(ushort_t* ldsbuf,
                                          const ushort_t* __restrict__ A,
                                          int m0, int kt, int tid) {
    int g = (tid & 3) ^ ((tid >> 3) & 3);    // pre-swizzled global 16B-slot
    int row = tid >> 2;                       // 0..127
    load_lds16(A + (size_t)(m0 + row) * KD + kt * 32 + g * 8,
               ldsbuf + (tid >> 6) * 512);
}
__device__ __forceinline__ void stageB256(ushort_t* ldsbuf,
                                          const ushort_t* __restrict__ xp,
                                          int n0, int kt, int tid) {
    int g = (tid & 3) ^ ((tid >> 3) & 3);
    int cs = kt / 7;                          // 0..7 (compiler: magic mul)
    int tap = kt - cs * 7;                    // 0..6
    const ushort_t* base = xp + (size_t)(n0 >> 11) * (LP * 256)
                              + (size_t)((n0 & 2047) + tap) * 256 + cs * 32 + g * 8;
#pragma unroll
    for (int j = 0; j < 2; ++j) {
        int row = j * 128 + (tid >> 2);
        load_lds16(base + (size_t)row * 256,
                   ldsbuf + 4096 + j * 4096 + (tid >> 6) * 512);
    }
}

template <int VMC, bool PF>
__device__ __forceinline__ void kstepN(const ushort_t* __restrict__ A,
                                       const ushort_t* __restrict__ xp,
                                       ushort_t* lds, int m0, int n0, int kt,
                                       int tid, int wr, int wc,
                                       int r15, int u, f32x4 (&acc)[4][4]) {
    asm volatile("s_waitcnt vmcnt(%0)" :: "n"(VMC) : "memory");
    __builtin_amdgcn_s_barrier();
    const ushort_t* buf = lds + (size_t)(kt % 3) * BUFU;
    const ushort_t* pa = buf + (wr * 64 + r15) * 32 + u * 8;
    const ushort_t* pb = buf + 4096 + (wc * 64 + r15) * 32 + u * 8;
    bf16x8 af[4], bq[4];
#pragma unroll
    for (int i = 0; i < 4; ++i) af[i] = *(const bf16x8*)(pa + i * 512);
#pragma unroll
    for (int j = 0; j < 4; ++j) bq[j] = *(const bf16x8*)(pb + j * 512);
    if (PF) {
        ushort_t* nb = lds + (size_t)((kt + 2) % 3) * BUFU;
        stageA128(nb, A,  m0, kt + 2, tid);
        stageB256(nb, xp, n0, kt + 2, tid);
    }
    __builtin_amdgcn_s_setprio(1);
#pragma unroll
    for (int i = 0; i < 4; ++i)
#pragma unroll
        for (int j = 0; j < 4; ++j)
            acc[i][j] = __builtin_amdgcn_mfma_f32_16x16x32_bf16(af[i], bq[j], acc[i][j], 0, 0, 0);
    __builtin_amdgcn_s_setprio(0);
}

__global__ __launch_bounds__(512, 4) void gemm128n_off_fused(const ushort_t* __restrict__ A,
                                                             const ushort_t* __restrict__ xp,
                                                             const float* __restrict__ boff,
                                                             const float* __restrict__ x,
                                                             ushort_t* __restrict__ s) {
    __shared__ __align__(16) ushort_t lds[3 * BUFU];     // 72 KiB ring -> 2 blocks/CU
    constexpr int NT = NTOT / 256;                        // 64 n-tiles
    constexpr int NWG = (MOFF / 128) * NT;                // 1792 (%8==0, 7 exact rounds)
    int bid = blockIdx.x;
    int wg = (bid & 7) * (NWG / 8) + (bid >> 3);          // XCD-bijective swizzle
    int mt = wg / NT, nt = wg % NT;
    int m0 = mt * 128, n0 = nt * 256;
    int tid = threadIdx.x, wid = tid >> 6, lane = tid & 63;
    int wr = wid >> 2, wc = wid & 3;
    int r15 = lane & 15, kh = lane >> 4;
    int u = kh ^ ((r15 >> 1) & 3);                        // swizzled read slot

    f32x4 acc[4][4] = {};

    stageA128(lds,        A,  m0, 0, tid);
    stageB256(lds,        xp, n0, 0, tid);
    stageA128(lds + BUFU, A,  m0, 1, tid);
    stageB256(lds + BUFU, xp, n0, 1, tid);

    for (int kt = 0; kt < NKSTEPS - 2; ++kt)
        kstepN<3, true>(A, xp, lds, m0, n0, kt, tid, wr, wc, r15, u, acc);
    kstepN<3, false>(A, xp, lds, m0, n0, NKSTEPS - 2, tid, wr, wc, r15, u, acc);
    kstepN<0, false>(A, xp, lds, m0, n0, NKSTEPS - 1, tid, wr, wc, r15, u, acc);

    // ---- fused epilogue: bias + sigmoid + deformable lerp -> LDS transpose tile ----
    __syncthreads();                     // all K-loop LDS reads done; ring is dead
    ushort_t* st = lds;                  // [256 n][72 pitch] bf16 tile (36.9 KB)
#pragma unroll
    for (int i = 0; i < 4; ++i) {
        int mloc = wr * 64 + i * 16 + kh * 4;             // local m (even)
        int ckb  = (m0 + mloc) >> 1;                       // global ck base (2 cks)
        int ckl  = mloc >> 1;                              // local ck (even, 0..62)
        float bo0 = boff[ckb],     bm0 = boff[KD + ckb];
        float bo1 = boff[ckb + 1], bm1 = boff[KD + ckb + 1];
        int c0 = ckb / 7,       kk0 = ckb - c0 * 7;
        int c1 = (ckb + 1) / 7, kk1 = (ckb + 1) - c1 * 7;
#pragma unroll
        for (int j = 0; j < 4; ++j) {
            int nl = wc * 64 + j * 16 + r15;
            int n = n0 + nl;
            int b = n >> 11, l = n & 2047;
            const float* xb_ = x + (size_t)b * (CC * LL);
            f32x4 v = acc[i][j];
            ushort2 o2;
#pragma unroll
            for (int p = 0; p < 2; ++p) {
                float offv = v[2 * p]     + (p ? bo1 : bo0);
                float mpre = v[2 * p + 1] + (p ? bm1 : bm0);
                int c = p ? c1 : c0, kk = p ? kk1 : kk0;
                float mask = 1.0f / (1.0f + __expf(-mpre));
                float pos = offv + (float)(l - PADc + kk);
                float p0f = floorf(pos);
                float frac = pos - p0f;
                int p0 = (int)p0f;
                const float* xr = xb_ + (size_t)c * LL;
                float x0 = ((unsigned)p0 < (unsigned)LL) ? xr[p0] : 0.0f;
                float x1 = ((unsigned)(p0 + 1) < (unsigned)LL) ? xr[p0 + 1] : 0.0f;
                float sv = (x0 + (x1 - x0) * frac) * mask;
                if (p) o2.y = f2bf(sv); else o2.x = f2bf(sv);
            }
            *(ushort2*)(st + nl * 72 + ckl) = o2;
        }
    }
    __syncthreads();
    // coalesced store-back: 256 rows x 128B; 8 lanes x ushort8 per row, 4 passes
    int srow = tid >> 3;                 // 0..63
    int scol = tid & 7;                  // 0..7
    int ck0g = m0 >> 1;
#pragma unroll
    for (int pass = 0; pass < 4; ++pass) {
        int nl = pass * 64 + srow;
        ushort8 v8 = *(const ushort8*)(st + nl * 72 + scol * 8);
        *(ushort8*)(s + (size_t)(n0 + nl) * KD + ck0g + scol * 8) = v8;
    }
}

// ==================== 128x128 counted-vmcnt GEMM (main conv, unchanged) ====================
__device__ __forceinline__ void stage128(ushort_t* ldsbuf,
                                         const ushort_t* __restrict__ A,
                                         const ushort_t* __restrict__ Bt,
                                         int m0, int n0, int kt,
                                         int wid, int lane) {
    int t = wid * 64 + lane;
    int g = (t & 3) ^ ((t >> 3) & 3);
#pragma unroll
    for (int j = 0; j < 2; ++j) {
        int row = j * 64 + (t >> 2);
        load_lds16(A  + (size_t)(m0 + row) * KD + kt * 32 + g * 8,
                   ldsbuf + j * 2048 + wid * 512);
        load_lds16(Bt + (size_t)(n0 + row) * KD + kt * 32 + g * 8,
                   ldsbuf + 4096 + j * 2048 + wid * 512);
    }
}

template <int VMCN>
__device__ __forceinline__ void kstep128(const ushort_t* __restrict__ A,
                                         const ushort_t* __restrict__ Bt,
                                         ushort_t* lds, int m0, int n0, int kt,
                                         int wid, int lane, int wr, int wc,
                                         int r15, int u, f32x4 (&acc)[4][4]) {
    asm volatile("s_waitcnt vmcnt(%0)" :: "n"(VMCN) : "memory");
    __builtin_amdgcn_s_barrier();
    const ushort_t* buf = lds + (size_t)(kt & 3) * 8192;
    const ushort_t* pa = buf + (wr * 64 + r15) * 32 + u * 8;
    const ushort_t* pb = buf + 4096 + (wc * 64 + r15) * 32 + u * 8;
    bf16x8 af[4], bq[4];
#pragma unroll
    for (int i = 0; i < 4; ++i) af[i] = *(const bf16x8*)(pa + i * 512);
#pragma unroll
    for (int j = 0; j < 4; ++j) bq[j] = *(const bf16x8*)(pb + j * 512);
    if (kt + 3 < NKSTEPS)
        stage128(lds + (size_t)((kt + 3) & 3) * 8192, A, Bt, m0, n0, kt + 3, wid, lane);
    __builtin_amdgcn_s_setprio(1);
#pragma unroll
    for (int i = 0; i < 4; ++i)
#pragma unroll
        for (int j = 0; j < 4; ++j)
            acc[i][j] = __builtin_amdgcn_mfma_f32_16x16x32_bf16(af[i], bq[j], acc[i][j], 0, 0, 0);
    __builtin_amdgcn_s_setprio(0);
}

__global__ __launch_bounds__(256, 2) void gemm128_out(const ushort_t* __restrict__ A,
                                                      const ushort_t* __restrict__ Bt,
                                                      const float* __restrict__ bvec,
                                                      float* __restrict__ Dout) {
    __shared__ __align__(16) ushort_t lds[4 * 8192];     // 64 KiB ring
    constexpr int NT = NTOT / 128;
    constexpr int NWG = (OUTC / 128) * NT;                // 256 (%8==0)
    int bid = blockIdx.x;
    int wg = (bid & 7) * (NWG / 8) + (bid >> 3);
    int mt = wg / NT, nt = wg % NT;
    int m0 = mt * 128, n0 = nt * 128;
    int tid = threadIdx.x, wid = tid >> 6, lane = tid & 63;
    int wr = wid >> 1, wc = wid & 1;
    int r15 = lane & 15, kh = lane >> 4;
    int u = kh ^ ((r15 >> 1) & 3);

    f32x4 acc[4][4] = {};

    stage128(lds,            A, Bt, m0, n0, 0, wid, lane);
    stage128(lds + 8192,     A, Bt, m0, n0, 1, wid, lane);
    stage128(lds + 2 * 8192, A, Bt, m0, n0, 2, wid, lane);

    for (int kt = 0; kt < NKSTEPS - 2; ++kt)
        kstep128<8>(A, Bt, lds, m0, n0, kt, wid, lane, wr, wc, r15, u, acc);
    kstep128<4>(A, Bt, lds, m0, n0, NKSTEPS - 2, wid, lane, wr, wc, r15, u, acc);
    kstep128<0>(A, Bt, lds, m0, n0, NKSTEPS - 1, wid, lane, wr, wc, r15, u, acc);

    int rbase = kh * 4;
#pragma unroll
    for (int i = 0; i < 4; ++i)
#pragma unroll
        for (int j = 0; j < 4; ++j) {
            int m = m0 + wr * 64 + i * 16 + rbase;
            int n = n0 + wc * 64 + j * 16 + r15;
            int b = n >> 11, l = n & 2047;
#pragma unroll
            for (int r = 0; r < 4; ++r) {
                float val = acc[i][j][r] + bvec[m + r];
                Dout[((size_t)(b * OUTC + (m + r))) * LL + l] = val;
            }
        }
}

// -------------------- launch --------------------
extern "C" void kernel_launch(void* const* d_in, const int* in_sizes, int n_in,
                              void* d_out, int out_size, void* d_ws, size_t ws_size,
                              hipStream_t stream) {
    const float* x      = (const float*)d_in[0];   // (8,256,2048)
    const float* w_off  = (const float*)d_in[1];   // (3584,256,7)
    const float* b_off  = (const float*)d_in[2];   // (3584,)
    const float* weight = (const float*)d_in[3];   // (256,256,7)
    const float* bias   = (const float*)d_in[4];   // (256,)
    float* out = (float*)d_out;                    // (8,256,2048)

    ushort_t* w = (ushort_t*)d_ws;
    ushort_t* wb  = w;                       // MOFF*KD   = 6,422,528 (c-major/tap-inner, row-permuted)
    ushort_t* wtb = wb  + MOFF * KD;         // OUTC*KD   =   458,752
    ushort_t* xp  = wtb + OUTC * KD;         // BB*LP*256 = 4,206,592 (padded transpose)
    ushort_t* s   = xp  + BB * LP * 256;     // NTOT*KD   = 29,360,128

    castperm_woff<<<(MOFF * KD + 255) / 256, 256, 0, stream>>>(w_off, wb);
    cast_k<<<(114688 + 255) / 256, 256, 0, stream>>>((const float4*)weight, wtb, 114688);
    xpose_k<<<512, 256, 0, stream>>>(x, xp);

    // offset conv (tap-decomposed B from xp, c-major K) + fused sampling: writes s[n][ck]
    gemm128n_off_fused<<<(MOFF / 128) * (NTOT / 256), 512, 0, stream>>>(wb, xp, b_off, x, s);

    // main conv: [256 x 1792] * [1792 x 16384]
    gemm128_out<<<(OUTC / 128) * (NTOT / 128), 256, 0, stream>>>(wtb, s, bias, out);
}

// Round 14
// 260.549 us; speedup vs baseline: 1.7742x; 1.0233x over previous
//
#include <hip/hip_runtime.h>

typedef unsigned short ushort_t;
typedef __attribute__((ext_vector_type(8))) short bf16x8;
typedef __attribute__((ext_vector_type(4))) float f32x4;
typedef __attribute__((ext_vector_type(8))) unsigned short ushort8;

// Problem geometry (compile-time)
constexpr int BB   = 8;
constexpr int CC   = 256;
constexpr int OUTC = 256;
constexpr int KK   = 7;
constexpr int LL   = 2048;
constexpr int PADc = 3;
constexpr int KD   = CC * KK;        // 1792 reduction dim
constexpr int MOFF = CC * KK * 2;    // 3584 offset-conv out channels
constexpr int NTOT = BB * LL;        // 16384
constexpr int NKSTEPS = KD / 32;     // 56
constexpr int LP   = LL + 6;         // 2054 padded length
constexpr int BUFU = 12288;          // ring buffer (24 KB: A 8K + B 16K) in ushorts

__device__ __forceinline__ ushort_t f2bf(float f) {
    unsigned u = __float_as_uint(f);
    unsigned r = (u + 0x7fffu + ((u >> 16) & 1u)) >> 16;  // RNE
    return (ushort_t)r;
}

// -------------------- cast f32 -> bf16 (vectorized, main-conv weight) --------------------
__global__ __launch_bounds__(256) void cast_k(const float4* __restrict__ src,
                                              ushort_t* __restrict__ dst, int n4) {
    int i = blockIdx.x * 256 + threadIdx.x;
    if (i >= n4) return;
    float4 v = src[i];
    ushort4 o;
    o.x = f2bf(v.x); o.y = f2bf(v.y); o.z = f2bf(v.z); o.w = f2bf(v.w);
    *(ushort4*)(dst + (size_t)i * 4) = o;
}

// ------ cast + permute w_off into c-major/tap-inner K layout (LDS transpose, coalesced) ------
// dst[dr][q], q = cs*224 + tap*32 + cl  <->  (c = cs*32+cl, kk = tap);
// src row r = (dr&1) ? KD + dr/2 : dr/2.  One block per dr: coalesced float4 read of
// src row into LDS, then each thread t<224 writes one dest-contiguous ushort8
// (d = 8t..8t+7 stays within one (cs,tap) block since 8|32; LDS gather stride 7 words
// is 28 distinct banks per cs-group, 2-way across groups = free).
__global__ __launch_bounds__(256) void castperm_woff(const float* __restrict__ src,
                                                     ushort_t* __restrict__ dst) {
    __shared__ float row[KD];
    int dr = blockIdx.x;
    int r = (dr & 1) ? (KD + (dr >> 1)) : (dr >> 1);
    int t = threadIdx.x;
    const float4* s4 = (const float4*)(src) + (size_t)r * (KD / 4);
    float4* l4 = (float4*)row;
    if (t < 224) {
        l4[t]       = s4[t];
        l4[t + 224] = s4[t + 224];
    }
    __syncthreads();
    if (t < 224) {
        int cs   = t / 28;
        int rem8 = 8 * t - cs * 224;
        int tap  = rem8 >> 5;
        int cl0  = rem8 & 31;
        int base = (cs * 32 + cl0) * 7 + tap;
        ushort8 o;
#pragma unroll
        for (int e = 0; e < 8; ++e)
            o[e] = f2bf(row[base + 7 * e]);
        *(ushort8*)(dst + (size_t)dr * KD + 8 * t) = o;
    }
}

// -------------------- padded transpose: xp[b][l+3][c] = x[b][c][l] --------------------
__global__ __launch_bounds__(256) void xpose_k(const float* __restrict__ x,
                                               ushort_t* __restrict__ xp) {
    __shared__ float tile[32][257];
    int bid = blockIdx.x;                 // 8 b x 8 ltiles x 8 cchunks = 512
    int b  = bid >> 6;
    int l0 = ((bid >> 3) & 7) * 256;
    int c0 = (bid & 7) * 32;
    int tid = threadIdx.x;
    const float* xb = x + (size_t)b * (CC * LL);
    ushort_t* xpb = xp + (size_t)b * (LP * 256);
#pragma unroll 4
    for (int k = 0; k < 32; ++k)
        tile[k][tid] = xb[(size_t)(c0 + k) * LL + l0 + tid];
    __syncthreads();
    int lp = l0 + tid + 3;
#pragma unroll
    for (int q = 0; q < 8; ++q) {
        ushort4 v;
        v.x = f2bf(tile[4 * q + 0][tid]);
        v.y = f2bf(tile[4 * q + 1][tid]);
        v.z = f2bf(tile[4 * q + 2][tid]);
        v.w = f2bf(tile[4 * q + 3][tid]);
        *(ushort4*)(xpb + (size_t)lp * 256 + c0 + 4 * q) = v;
    }
    if ((bid & 63) == 0) {
#pragma unroll
        for (int r = 0; r < 6; ++r) {
            int glp = (r < 3) ? r : (2048 + r);
            xpb[glp * 256 + tid] = 0;
        }
    }
}

// -------------------- async global->LDS 16B --------------------
__device__ __forceinline__ void load_lds16(const ushort_t* g, ushort_t* l) {
    __builtin_amdgcn_global_load_lds(
        (const __attribute__((address_space(1))) unsigned int*)g,
        (__attribute__((address_space(3))) unsigned int*)l, 16, 0, 0);
}

// ==================== 128x256 counted-vmcnt GEMM + tap-B (c-major) + fused sampling ====================
// ROUND-9 VERIFIED OPTIMUM (237 us, MfmaUtil 41.5%, FETCH 136MB) — unchanged.
// Tile M=128 x N=256, 8 waves (2M x 4N), per-wave 64x64 (acc[4][4]).
// Ring-3 LDS (3 x 24 KB = 72 KB -> 2 blocks/CU), ONE vmcnt gate + ONE barrier per
// BK=32 step, stage distance 2, per-lane 3 loads/kstep -> gates vmcnt(3)/(3)/(0).
// K order is c-major/tap-inner: kt -> cs = kt/7, tap = kt%7, so consecutive ksteps
// re-read a 1-row-shifted xp window (L2-hot) instead of 7 separated tap passes.
__device__ __forceinline__ void stageA128(ushort_t* ldsbuf,
                                          const ushort_t* __restrict__ A,
                                          int m0, int kt, int tid) {
    int g = (tid & 3) ^ ((tid >> 3) & 3);    // pre-swizzled global 16B-slot
    int row = tid >> 2;                       // 0..127
    load_lds16(A + (size_t)(m0 + row) * KD + kt * 32 + g * 8,
               ldsbuf + (tid >> 6) * 512);
}
__device__ __forceinline__ void stageB256(ushort_t* ldsbuf,
                                          const ushort_t* __restrict__ xp,
                                          int n0, int kt, int tid) {
    int g = (tid & 3) ^ ((tid >> 3) & 3);
    int cs = kt / 7;                          // 0..7 (compiler: magic mul)
    int tap = kt - cs * 7;                    // 0..6
    const ushort_t* base = xp + (size_t)(n0 >> 11) * (LP * 256)
                              + (size_t)((n0 & 2047) + tap) * 256 + cs * 32 + g * 8;
#pragma unroll
    for (int j = 0; j < 2; ++j) {
        int row = j * 128 + (tid >> 2);
        load_lds16(base + (size_t)row * 256,
                   ldsbuf + 4096 + j * 4096 + (tid >> 6) * 512);
    }
}

template <int VMC, bool PF>
__device__ __forceinline__ void kstepN(const ushort_t* __restrict__ A,
                                       const ushort_t* __restrict__ xp,
                                       ushort_t* lds, int m0, int n0, int kt,
                                       int tid, int wr, int wc,
                                       int r15, int u, f32x4 (&acc)[4][4]) {
    asm volatile("s_waitcnt vmcnt(%0)" :: "n"(VMC) : "memory");
    __builtin_amdgcn_s_barrier();
    const ushort_t* buf = lds + (size_t)(kt % 3) * BUFU;
    const ushort_t* pa = buf + (wr * 64 + r15) * 32 + u * 8;
    const ushort_t* pb = buf + 4096 + (wc * 64 + r15) * 32 + u * 8;
    bf16x8 af[4], bq[4];
#pragma unroll
    for (int i = 0; i < 4; ++i) af[i] = *(const bf16x8*)(pa + i * 512);
#pragma unroll
    for (int j = 0; j < 4; ++j) bq[j] = *(const bf16x8*)(pb + j * 512);
    if (PF) {
        ushort_t* nb = lds + (size_t)((kt + 2) % 3) * BUFU;
        stageA128(nb, A,  m0, kt + 2, tid);
        stageB256(nb, xp, n0, kt + 2, tid);
    }
    __builtin_amdgcn_s_setprio(1);
#pragma unroll
    for (int i = 0; i < 4; ++i)
#pragma unroll
        for (int j = 0; j < 4; ++j)
            acc[i][j] = __builtin_amdgcn_mfma_f32_16x16x32_bf16(af[i], bq[j], acc[i][j], 0, 0, 0);
    __builtin_amdgcn_s_setprio(0);
}

__global__ __launch_bounds__(512, 4) void gemm128n_off_fused(const ushort_t* __restrict__ A,
                                                             const ushort_t* __restrict__ xp,
                                                             const float* __restrict__ boff,
                                                             const float* __restrict__ x,
                                                             ushort_t* __restrict__ s) {
    __shared__ __align__(16) ushort_t lds[3 * BUFU];     // 72 KiB ring -> 2 blocks/CU
    constexpr int NT = NTOT / 256;                        // 64 n-tiles
    constexpr int NWG = (MOFF / 128) * NT;                // 1792 (%8==0, 7 exact rounds)
    int bid = blockIdx.x;
    int wg = (bid & 7) * (NWG / 8) + (bid >> 3);          // XCD-bijective swizzle
    int mt = wg / NT, nt = wg % NT;
    int m0 = mt * 128, n0 = nt * 256;
    int tid = threadIdx.x, wid = tid >> 6, lane = tid & 63;
    int wr = wid >> 2, wc = wid & 3;
    int r15 = lane & 15, kh = lane >> 4;
    int u = kh ^ ((r15 >> 1) & 3);                        // swizzled read slot

    f32x4 acc[4][4] = {};

    stageA128(lds,        A,  m0, 0, tid);
    stageB256(lds,        xp, n0, 0, tid);
    stageA128(lds + BUFU, A,  m0, 1, tid);
    stageB256(lds + BUFU, xp, n0, 1, tid);

    for (int kt = 0; kt < NKSTEPS - 2; ++kt)
        kstepN<3, true>(A, xp, lds, m0, n0, kt, tid, wr, wc, r15, u, acc);
    kstepN<3, false>(A, xp, lds, m0, n0, NKSTEPS - 2, tid, wr, wc, r15, u, acc);
    kstepN<0, false>(A, xp, lds, m0, n0, NKSTEPS - 1, tid, wr, wc, r15, u, acc);

    // ---- fused epilogue: bias + sigmoid + deformable lerp -> LDS transpose tile ----
    __syncthreads();                     // all K-loop LDS reads done; ring is dead
    ushort_t* st = lds;                  // [256 n][72 pitch] bf16 tile (36.9 KB)
#pragma unroll
    for (int i = 0; i < 4; ++i) {
        int mloc = wr * 64 + i * 16 + kh * 4;             // local m (even)
        int ckb  = (m0 + mloc) >> 1;                       // global ck base (2 cks)
        int ckl  = mloc >> 1;                              // local ck (even, 0..62)
        float bo0 = boff[ckb],     bm0 = boff[KD + ckb];
        float bo1 = boff[ckb + 1], bm1 = boff[KD + ckb + 1];
        int c0 = ckb / 7,       kk0 = ckb - c0 * 7;
        int c1 = (ckb + 1) / 7, kk1 = (ckb + 1) - c1 * 7;
#pragma unroll
        for (int j = 0; j < 4; ++j) {
            int nl = wc * 64 + j * 16 + r15;
            int n = n0 + nl;
            int b = n >> 11, l = n & 2047;
            const float* xb_ = x + (size_t)b * (CC * LL);
            f32x4 v = acc[i][j];
            ushort2 o2;
#pragma unroll
            for (int p = 0; p < 2; ++p) {
                float offv = v[2 * p]     + (p ? bo1 : bo0);
                float mpre = v[2 * p + 1] + (p ? bm1 : bm0);
                int c = p ? c1 : c0, kk = p ? kk1 : kk0;
                float mask = 1.0f / (1.0f + __expf(-mpre));
                float pos = offv + (float)(l - PADc + kk);
                float p0f = floorf(pos);
                float frac = pos - p0f;
                int p0 = (int)p0f;
                const float* xr = xb_ + (size_t)c * LL;
                float x0 = ((unsigned)p0 < (unsigned)LL) ? xr[p0] : 0.0f;
                float x1 = ((unsigned)(p0 + 1) < (unsigned)LL) ? xr[p0 + 1] : 0.0f;
                float sv = (x0 + (x1 - x0) * frac) * mask;
                if (p) o2.y = f2bf(sv); else o2.x = f2bf(sv);
            }
            *(ushort2*)(st + nl * 72 + ckl) = o2;
        }
    }
    __syncthreads();
    // coalesced store-back: 256 rows x 128B; 8 lanes x ushort8 per row, 4 passes
    int srow = tid >> 3;                 // 0..63
    int scol = tid & 7;                  // 0..7
    int ck0g = m0 >> 1;
#pragma unroll
    for (int pass = 0; pass < 4; ++pass) {
        int nl = pass * 64 + srow;
        ushort8 v8 = *(const ushort8*)(st + nl * 72 + scol * 8);
        *(ushort8*)(s + (size_t)(n0 + nl) * KD + ck0g + scol * 8) = v8;
    }
}

// ==================== 128x128 counted-vmcnt GEMM (main conv, unchanged) ====================
__device__ __forceinline__ void stage128(ushort_t* ldsbuf,
                                         const ushort_t* __restrict__ A,
                                         const ushort_t* __restrict__ Bt,
                                         int m0, int n0, int kt,
                                         int wid, int lane) {
    int t = wid * 64 + lane;
    int g = (t & 3) ^ ((t >> 3) & 3);
#pragma unroll
    for (int j = 0; j < 2; ++j) {
        int row = j * 64 + (t >> 2);
        load_lds16(A  + (size_t)(m0 + row) * KD + kt * 32 + g * 8,
                   ldsbuf + j * 2048 + wid * 512);
        load_lds16(Bt + (size_t)(n0 + row) * KD + kt * 32 + g * 8,
                   ldsbuf + 4096 + j * 2048 + wid * 512);
    }
}

template <int VMCN>
__device__ __forceinline__ void kstep128(const ushort_t* __restrict__ A,
                                         const ushort_t* __restrict__ Bt,
                                         ushort_t* lds, int m0, int n0, int kt,
                                         int wid, int lane, int wr, int wc,
                                         int r15, int u, f32x4 (&acc)[4][4]) {
    asm volatile("s_waitcnt vmcnt(%0)" :: "n"(VMCN) : "memory");
    __builtin_amdgcn_s_barrier();
    const ushort_t* buf = lds + (size_t)(kt & 3) * 8192;
    const ushort_t* pa = buf + (wr * 64 + r15) * 32 + u * 8;
    const ushort_t* pb = buf + 4096 + (wc * 64 + r15) * 32 + u * 8;
    bf16x8 af[4], bq[4];
#pragma unroll
    for (int i = 0; i < 4; ++i) af[i] = *(const bf16x8*)(pa + i * 512);
#pragma unroll
    for (int j = 0; j < 4; ++j) bq[j] = *(const bf16x8*)(pb + j * 512);
    if (kt + 3 < NKSTEPS)
        stage128(lds + (size_t)((kt + 3) & 3) * 8192, A, Bt, m0, n0, kt + 3, wid, lane);
    __builtin_amdgcn_s_setprio(1);
#pragma unroll
    for (int i = 0; i < 4; ++i)
#pragma unroll
        for (int j = 0; j < 4; ++j)
            acc[i][j] = __builtin_amdgcn_mfma_f32_16x16x32_bf16(af[i], bq[j], acc[i][j], 0, 0, 0);
    __builtin_amdgcn_s_setprio(0);
}

__global__ __launch_bounds__(256, 2) void gemm128_out(const ushort_t* __restrict__ A,
                                                      const ushort_t* __restrict__ Bt,
                                                      const float* __restrict__ bvec,
                                                      float* __restrict__ Dout) {
    __shared__ __align__(16) ushort_t lds[4 * 8192];     // 64 KiB ring
    constexpr int NT = NTOT / 128;
    constexpr int NWG = (OUTC / 128) * NT;                // 256 (%8==0)
    int bid = blockIdx.x;
    int wg = (bid & 7) * (NWG / 8) + (bid >> 3);
    int mt = wg / NT, nt = wg % NT;
    int m0 = mt * 128, n0 = nt * 128;
    int tid = threadIdx.x, wid = tid >> 6, lane = tid & 63;
    int wr = wid >> 1, wc = wid & 1;
    int r15 = lane & 15, kh = lane >> 4;
    int u = kh ^ ((r15 >> 1) & 3);

    f32x4 acc[4][4] = {};

    stage128(lds,            A, Bt, m0, n0, 0, wid, lane);
    stage128(lds + 8192,     A, Bt, m0, n0, 1, wid, lane);
    stage128(lds + 2 * 8192, A, Bt, m0, n0, 2, wid, lane);

    for (int kt = 0; kt < NKSTEPS - 2; ++kt)
        kstep128<8>(A, Bt, lds, m0, n0, kt, wid, lane, wr, wc, r15, u, acc);
    kstep128<4>(A, Bt, lds, m0, n0, NKSTEPS - 2, wid, lane, wr, wc, r15, u, acc);
    kstep128<0>(A, Bt, lds, m0, n0, NKSTEPS - 1, wid, lane, wr, wc, r15, u, acc);

    int rbase = kh * 4;
#pragma unroll
    for (int i = 0; i < 4; ++i)
#pragma unroll
        for (int j = 0; j < 4; ++j) {
            int m = m0 + wr * 64 + i * 16 + rbase;
            int n = n0 + wc * 64 + j * 16 + r15;
            int b = n >> 11, l = n & 2047;
#pragma unroll
            for (int r = 0; r < 4; ++r) {
                float val = acc[i][j][r] + bvec[m + r];
                Dout[((size_t)(b * OUTC + (m + r))) * LL + l] = val;
            }
        }
}

// -------------------- launch --------------------
extern "C" void kernel_launch(void* const* d_in, const int* in_sizes, int n_in,
                              void* d_out, int out_size, void* d_ws, size_t ws_size,
                              hipStream_t stream) {
    const float* x      = (const float*)d_in[0];   // (8,256,2048)
    const float* w_off  = (const float*)d_in[1];   // (3584,256,7)
    const float* b_off  = (const float*)d_in[2];   // (3584,)
    const float* weight = (const float*)d_in[3];   // (256,256,7)
    const float* bias   = (const float*)d_in[4];   // (256,)
    float* out = (float*)d_out;                    // (8,256,2048)

    ushort_t* w = (ushort_t*)d_ws;
    ushort_t* wb  = w;                       // MOFF*KD   = 6,422,528 (c-major/tap-inner, row-permuted)
    ushort_t* wtb = wb  + MOFF * KD;         // OUTC*KD   =   458,752
    ushort_t* xp  = wtb + OUTC * KD;         // BB*LP*256 = 4,206,592 (padded transpose)
    ushort_t* s   = xp  + BB * LP * 256;     // NTOT*KD   = 29,360,128

    castperm_woff<<<MOFF, 256, 0, stream>>>(w_off, wb);
    cast_k<<<(114688 + 255) / 256, 256, 0, stream>>>((const float4*)weight, wtb, 114688);
    xpose_k<<<512, 256, 0, stream>>>(x, xp);

    // offset conv (tap-decomposed B from xp, c-major K) + fused sampling: writes s[n][ck]
    gemm128n_off_fused<<<(MOFF / 128) * (NTOT / 256), 512, 0, stream>>>(wb, xp, b_off, x, s);

    // main conv: [256 x 1792] * [1792 x 16384]
    gemm128_out<<<(OUTC / 128) * (NTOT / 128), 256, 0, stream>>>(wtb, s, bias, out);
}